// Round 1
// baseline (1045.763 us; speedup 1.0000x reference)
//
#include <hip/hip_runtime.h>
#include <stdint.h>

// Problem constants
// B=4, S=2048, D=512, H=8, DK=DV=64
typedef __attribute__((ext_vector_type(8))) short short8;
typedef __attribute__((ext_vector_type(4))) float f32x4;
typedef __attribute__((ext_vector_type(4))) unsigned short ushort4v;

__device__ __forceinline__ unsigned short f2bf(float f) {
    union { float f; uint32_t u; } v; v.f = f;
    return (unsigned short)((v.u + 0x7FFFu + ((v.u >> 16) & 1u)) >> 16);
}
__device__ __forceinline__ float bf2f(unsigned short h) {
    union { uint32_t u; float f; } v; v.u = ((uint32_t)h) << 16;
    return v.f;
}

// ---------------- Kernel 1: transpose weights to Wt[n][k] bf16 ----------------
__global__ __launch_bounds__(256) void prep_wt_kernel(
    const float* __restrict__ W0, const float* __restrict__ W1,
    const float* __restrict__ W2, const float* __restrict__ W3,
    unsigned short* __restrict__ Wt)
{
    const float* W = blockIdx.y == 0 ? W0 : blockIdx.y == 1 ? W1 : blockIdx.y == 2 ? W2 : W3;
    unsigned short* dst = Wt + (size_t)blockIdx.y * (512 * 512);
    int k = blockIdx.x >> 1;
    int n = ((blockIdx.x & 1) << 8) + threadIdx.x;
    dst[(size_t)n * 512 + k] = f2bf(W[(size_t)k * 512 + n]);
}

// ---------------- Kernel 2: Q/K/V projections ----------------
// which=0: Q -> [bh][s][64] bf16 ; which=1: K -> same ; which=2: V -> VT [bh][64][s]
__global__ __launch_bounds__(512) void proj_kernel(
    const float* __restrict__ inQ, const float* __restrict__ inK, const float* __restrict__ inV,
    const unsigned short* __restrict__ Wt,
    unsigned short* __restrict__ outQ, unsigned short* __restrict__ outK,
    unsigned short* __restrict__ outVT)
{
    const int which = blockIdx.y;
    const float* inp = which == 0 ? inQ : which == 1 ? inK : inV;
    const unsigned short* Wtb = Wt + (size_t)which * (512 * 512);
    const int tid = threadIdx.x;
    const int wid = tid >> 6, l = tid & 63;
    const int rt = wid >> 1, ch = wid & 1;
    const int lrow = l & 15, g = l >> 4;
    const int rowbase = blockIdx.x * 64;
    const int arow = rowbase + rt * 16 + lrow;

    f32x4 acc[16];
#pragma unroll
    for (int t = 0; t < 16; ++t) acc[t] = (f32x4){0.f, 0.f, 0.f, 0.f};

    for (int k0 = 0; k0 < 512; k0 += 32) {
        const float* ap = inp + (size_t)arow * 512 + k0 + g * 8;
        float4 a0 = *(const float4*)ap;
        float4 a1 = *(const float4*)(ap + 4);
        short8 af;
        af[0] = (short)f2bf(a0.x); af[1] = (short)f2bf(a0.y);
        af[2] = (short)f2bf(a0.z); af[3] = (short)f2bf(a0.w);
        af[4] = (short)f2bf(a1.x); af[5] = (short)f2bf(a1.y);
        af[6] = (short)f2bf(a1.z); af[7] = (short)f2bf(a1.w);
#pragma unroll
        for (int t = 0; t < 16; ++t) {
            const int n = ch * 256 + t * 16 + lrow;
            short8 bf = *(const short8*)(Wtb + (size_t)n * 512 + k0 + g * 8);
            acc[t] = __builtin_amdgcn_mfma_f32_16x16x32_bf16(af, bf, acc[t], 0, 0, 0);
        }
    }

    if (which == 2) {
#pragma unroll
        for (int t = 0; t < 16; ++t) {
            const int n = ch * 256 + t * 16 + lrow;
            const int hh = n >> 6, dd = n & 63;
            const int row0 = rowbase + rt * 16 + g * 4;   // C-frag rows
            const int bb = row0 >> 11, s0 = row0 & 2047;
            ushort4v pk;
            pk[0] = f2bf(acc[t][0]); pk[1] = f2bf(acc[t][1]);
            pk[2] = f2bf(acc[t][2]); pk[3] = f2bf(acc[t][3]);
            *(ushort4v*)(outVT + ((size_t)(bb * 8 + hh) * 64 + dd) * 2048 + s0) = pk;
        }
    } else {
        unsigned short* dst = which == 0 ? outQ : outK;
#pragma unroll
        for (int t = 0; t < 16; ++t) {
            const int n = ch * 256 + t * 16 + lrow;
            const int hh = n >> 6, dd = n & 63;
#pragma unroll
            for (int r = 0; r < 4; ++r) {
                const int row = rowbase + rt * 16 + g * 4 + r;
                const int bb = row >> 11, s0 = row & 2047;
                dst[((size_t)(bb * 8 + hh) * 2048 + s0) * 64 + dd] = f2bf(acc[t][r]);
            }
        }
    }
}

// ---------------- Kernel 3: fused attention ----------------
// 1 WG = (b,h, 32 q-rows). P (unnormalized exp scores) bf16 [32][2048] in LDS,
// XOR-swizzled: byte = row*4096 + (colbyte ^ ((row&7)<<4)).
__global__ __launch_bounds__(512) void attn_kernel(
    const unsigned short* __restrict__ Qw, const unsigned short* __restrict__ Kw,
    const unsigned short* __restrict__ VT, const unsigned char* __restrict__ mask,
    float* __restrict__ attn_out, unsigned short* __restrict__ ctx)
{
    extern __shared__ char smem[];
    float* rowsum = (float*)(smem + 128 * 1024);
    // XCD-bijective remap: L%8 selects XCD; keep all q-blocks of one (b,h) on one XCD.
    const int L = blockIdx.x;
    const int xcd = L & 7, idx = L >> 3;
    const int q6 = idx & 63;
    const int bh = ((idx >> 6) << 3) | xcd;
    const int b = bh >> 3, h = bh & 7;
    const int qg0 = q6 * 32;
    const int tid = threadIdx.x, wid = tid >> 6, l = tid & 63;
    const int lrow = l & 15, g = l >> 4;

    if (tid < 32) rowsum[tid] = 0.f;
    __syncthreads();

    // ---- Phase 1: QK^T, mask, exp, rowsum, store P to LDS ----
    {
        const int qt = wid & 1, stripe = wid >> 1;
        const int q0 = qt * 16;
        const unsigned short* qp = Qw + ((size_t)bh * 2048 + qg0 + q0 + lrow) * 64 + g * 8;
        const short8 qf0 = *(const short8*)qp;
        const short8 qf1 = *(const short8*)(qp + 32);
        float psum[4] = {0.f, 0.f, 0.f, 0.f};
        const size_t mbase = ((size_t)b * 2048 + qg0 + q0 + g * 4) * 2048;
        for (int i = 0; i < 32; ++i) {
            const int kbase = (stripe + i * 4) * 16;
            const unsigned short* kp = Kw + ((size_t)bh * 2048 + kbase + lrow) * 64 + g * 8;
            short8 kf0 = *(const short8*)kp;
            short8 kf1 = *(const short8*)(kp + 32);
            f32x4 sc = (f32x4){0.f, 0.f, 0.f, 0.f};
            sc = __builtin_amdgcn_mfma_f32_16x16x32_bf16(qf0, kf0, sc, 0, 0, 0);
            sc = __builtin_amdgcn_mfma_f32_16x16x32_bf16(qf1, kf1, sc, 0, 0, 0);
#pragma unroll
            for (int r = 0; r < 4; ++r) {
                const int qrl = q0 + g * 4 + r;   // local row 0..31
                const unsigned char m = mask[mbase + (size_t)r * 2048 + kbase + lrow];
                const float e = m ? 0.f : __expf(sc[r] * 0.125f);
                psum[r] += e;
                *(unsigned short*)(smem + qrl * 4096 +
                                   (((kbase + lrow) * 2) ^ ((qrl & 7) << 4))) = f2bf(e);
            }
        }
#pragma unroll
        for (int r = 0; r < 4; ++r) {
            psum[r] += __shfl_xor(psum[r], 1);
            psum[r] += __shfl_xor(psum[r], 2);
            psum[r] += __shfl_xor(psum[r], 4);
            psum[r] += __shfl_xor(psum[r], 8);
        }
        if (lrow == 0) {
#pragma unroll
            for (int r = 0; r < 4; ++r) atomicAdd(&rowsum[q0 + g * 4 + r], psum[r]);
        }
    }
    __syncthreads();

    // ---- Phase 2: waves 0-3 -> PV + context; waves 4-7 -> stream attn to HBM ----
    if (wid < 4) {
        const int ct = wid;
        f32x4 accA = (f32x4){0.f,0.f,0.f,0.f}, accB = (f32x4){0.f,0.f,0.f,0.f};
        const unsigned short* vbase = VT + ((size_t)bh * 64 + ct * 16 + lrow) * 2048;
        const int rA = lrow, rB = 16 + lrow;
        const int swA = (rA & 7) << 4, swB = (rB & 7) << 4;
#pragma unroll 4
        for (int ks = 0; ks < 64; ++ks) {
            short8 bf = *(const short8*)(vbase + ks * 32 + g * 8);
            const int kbyte = ks * 64 + g * 16;
            short8 a0 = *(const short8*)(smem + rA * 4096 + (kbyte ^ swA));
            short8 a1 = *(const short8*)(smem + rB * 4096 + (kbyte ^ swB));
            accA = __builtin_amdgcn_mfma_f32_16x16x32_bf16(a0, bf, accA, 0, 0, 0);
            accB = __builtin_amdgcn_mfma_f32_16x16x32_bf16(a1, bf, accB, 0, 0, 0);
        }
#pragma unroll
        for (int rt = 0; rt < 2; ++rt) {
            const f32x4 a = rt ? accB : accA;
#pragma unroll
            for (int r = 0; r < 4; ++r) {
                const int row = rt * 16 + g * 4 + r;
                const float rinv = 1.0f / rowsum[row];
                ctx[((size_t)b * 2048 + qg0 + row) * 512 + h * 64 + ct * 16 + lrow] =
                    f2bf(a[r] * rinv);
            }
        }
    } else {
        const int r0 = (wid - 4) * 8;
        for (int rr = 0; rr < 8; ++rr) {
            const int row = r0 + rr;
            const float rinv = 1.0f / rowsum[row];
            float* gp = attn_out + ((size_t)bh * 2048 + qg0 + row) * 2048;
            const int sw = (row & 7) << 4;
            const int rbase = row * 4096;
#pragma unroll 4
            for (int c0 = 0; c0 < 2048; c0 += 128) {
                const int off = rbase + (((c0 + 2 * l) * 2) ^ sw);
                const uint32_t u = *(const uint32_t*)(smem + off);
                float2 o;
                o.x = bf2f((unsigned short)(u & 0xFFFFu)) * rinv;
                o.y = bf2f((unsigned short)(u >> 16)) * rinv;
                *(float2*)(gp + c0 + 2 * l) = o;
            }
        }
    }
}

// ---------------- Kernel 4: fc + residual + LayerNorm ----------------
__global__ __launch_bounds__(512) void fc_ln_kernel(
    const unsigned short* __restrict__ ctx, const unsigned short* __restrict__ Wtfc,
    const float* __restrict__ resid, const float* __restrict__ gamma,
    const float* __restrict__ beta, float* __restrict__ out)
{
    __shared__ float red[64][2][2];
    const int tid = threadIdx.x;
    const int wid = tid >> 6, l = tid & 63;
    const int rt = wid >> 1, ch = wid & 1;
    const int lrow = l & 15, g = l >> 4;
    const int rowbase = blockIdx.x * 64;
    const int arow = rowbase + rt * 16 + lrow;

    f32x4 acc[16];
#pragma unroll
    for (int t = 0; t < 16; ++t) acc[t] = (f32x4){0.f, 0.f, 0.f, 0.f};

    for (int k0 = 0; k0 < 512; k0 += 32) {
        short8 af = *(const short8*)(ctx + (size_t)arow * 512 + k0 + g * 8);
#pragma unroll
        for (int t = 0; t < 16; ++t) {
            const int n = ch * 256 + t * 16 + lrow;
            short8 bf = *(const short8*)(Wtfc + (size_t)n * 512 + k0 + g * 8);
            acc[t] = __builtin_amdgcn_mfma_f32_16x16x32_bf16(af, bf, acc[t], 0, 0, 0);
        }
    }

    float s1[4] = {0,0,0,0}, s2[4] = {0,0,0,0};
#pragma unroll
    for (int t = 0; t < 16; ++t) {
        const int n = ch * 256 + t * 16 + lrow;
#pragma unroll
        for (int r = 0; r < 4; ++r) {
            const int row = rowbase + rt * 16 + g * 4 + r;
            float v = acc[t][r] + resid[(size_t)row * 512 + n];
            acc[t][r] = v;
            s1[r] += v;
            s2[r] += v * v;
        }
    }
#pragma unroll
    for (int r = 0; r < 4; ++r) {
        s1[r] += __shfl_xor(s1[r], 1); s2[r] += __shfl_xor(s2[r], 1);
        s1[r] += __shfl_xor(s1[r], 2); s2[r] += __shfl_xor(s2[r], 2);
        s1[r] += __shfl_xor(s1[r], 4); s2[r] += __shfl_xor(s2[r], 4);
        s1[r] += __shfl_xor(s1[r], 8); s2[r] += __shfl_xor(s2[r], 8);
    }
    if (lrow == 0) {
#pragma unroll
        for (int r = 0; r < 4; ++r) {
            red[rt * 16 + g * 4 + r][ch][0] = s1[r];
            red[rt * 16 + g * 4 + r][ch][1] = s2[r];
        }
    }
    __syncthreads();
    float mean[4], rstd[4];
#pragma unroll
    for (int r = 0; r < 4; ++r) {
        const int rl = rt * 16 + g * 4 + r;
        const float S1 = red[rl][0][0] + red[rl][1][0];
        const float S2 = red[rl][0][1] + red[rl][1][1];
        mean[r] = S1 * (1.0f / 512.0f);
        const float var = S2 * (1.0f / 512.0f) - mean[r] * mean[r];
        rstd[r] = rsqrtf(var + 1e-5f);
    }
#pragma unroll
    for (int t = 0; t < 16; ++t) {
        const int n = ch * 256 + t * 16 + lrow;
        const float gm = gamma[n], bt = beta[n];
#pragma unroll
        for (int r = 0; r < 4; ++r) {
            const int row = rowbase + rt * 16 + g * 4 + r;
            out[(size_t)row * 512 + n] = (acc[t][r] - mean[r]) * rstd[r] * gm + bt;
        }
    }
}

// ---------------- Host launcher ----------------
extern "C" void kernel_launch(void* const* d_in, const int* in_sizes, int n_in,
                              void* d_out, int out_size, void* d_ws, size_t ws_size,
                              hipStream_t stream)
{
    (void)in_sizes; (void)n_in; (void)out_size; (void)ws_size;
    const float* inQ = (const float*)d_in[0];
    const float* inK = (const float*)d_in[1];
    const float* inV = (const float*)d_in[2];
    const unsigned char* mask = (const unsigned char*)d_in[3];  // np.bool_ -> 1 byte
    const float* WQ  = (const float*)d_in[4];
    const float* WK  = (const float*)d_in[5];
    const float* WV  = (const float*)d_in[6];
    const float* Wfc = (const float*)d_in[7];
    const float* gamma = (const float*)d_in[8];
    const float* beta  = (const float*)d_in[9];

    char* ws = (char*)d_ws;
    unsigned short* wsQ   = (unsigned short*)(ws);                           // 8 MB
    unsigned short* wsK   = (unsigned short*)(ws + ((size_t)8  << 20));      // 8 MB
    unsigned short* wsVT  = (unsigned short*)(ws + ((size_t)16 << 20));      // 8 MB
    unsigned short* wsCtx = (unsigned short*)(ws + ((size_t)24 << 20));      // 8 MB
    unsigned short* wsWt  = (unsigned short*)(ws + ((size_t)32 << 20));      // 2 MB

    float* out_ln   = (float*)d_out;
    float* out_attn = out_ln + (size_t)4 * 2048 * 512;

    prep_wt_kernel<<<dim3(1024, 4), dim3(256), 0, stream>>>(WQ, WK, WV, Wfc, wsWt);
    proj_kernel<<<dim3(128, 3), dim3(512), 0, stream>>>(inQ, inK, inV, wsWt, wsQ, wsK, wsVT);

    const int smem_bytes = 128 * 1024 + 128;
    hipFuncSetAttribute((const void*)attn_kernel,
                        hipFuncAttributeMaxDynamicSharedMemorySize, smem_bytes);
    attn_kernel<<<dim3(2048), dim3(512), smem_bytes, stream>>>(wsQ, wsK, wsVT, mask,
                                                               out_attn, wsCtx);
    fc_ln_kernel<<<dim3(128), dim3(512), 0, stream>>>(wsCtx, wsWt + (size_t)3 * 512 * 512,
                                                      inQ, gamma, beta, out_ln);
}